// Round 1
// baseline (153.768 us; speedup 1.0000x reference)
//
#include <hip/hip_runtime.h>
#include <hip/hip_bf16.h>

#define NN 64
#define CC 512
#define HW 48
#define LNSZ (CC * HW)   // 24576 per sample

typedef __attribute__((ext_vector_type(8))) short bf16x8;  // 8 bf16 (4 VGPRs)
typedef __attribute__((ext_vector_type(4))) float floatx4;

// ---- workspace layout (float offsets) ----
static const size_t WB_OFF   = 0;        // 1536x512 bf16 = 393216 float-slots
static const size_t BC_OFF   = 393216;   // 512 fp32 biases (theta ++ phi)
static const size_t S_OFF    = 393728;   // 3072 fp32 (attention scale, atomic)
static const size_t CXP_OFF  = 396928;   // [64][4][48] colsum partials
static const size_t CX2_OFF  = 409216;   // [64][4][48] colsumsq partials
static const size_t XB_OFF   = 422016;   // [64][48][512] bf16 = 786432 slots
static const size_t TP_OFF   = 1208448;  // ThPhi bf16 [64][48][512]
static const size_t YB_OFF   = 1994880;  // yb bf16 [64][48][512]
static const size_t UB_OFF   = 2781312;  // ub bf16 [64][48][512]
static const size_t PP_OFF   = 3567744;  // Pp bf16 [768][256] = 98304 slots
static const size_t ST2_OFF  = 3567744;  // ln2 stats [64][8] float2 — reuses Pp
                                         // region (Pp dead after dgemm_fused)
static const size_t YY_OFF   = 3666048;  // y fp32 [64][512][48]
static const size_t VV_OFF   = 5238912;  // v fp32 [64][512][48]

// block-level {sum, sumsq} reduction; valid result in thread 0
__device__ __forceinline__ void block_reduce2(float& sum, float& sq) {
  const int lane = threadIdx.x & 63, w = threadIdx.x >> 6;
#pragma unroll
  for (int off = 32; off > 0; off >>= 1) {
    sum += __shfl_down(sum, off, 64);
    sq  += __shfl_down(sq, off, 64);
  }
  __shared__ float rs[4], rq[4];
  if (lane == 0) { rs[w] = sum; rq[w] = sq; }
  __syncthreads();
  if (threadIdx.x == 0) {
    sum = rs[0] + rs[1] + rs[2] + rs[3];
    sq  = rq[0] + rq[1] + rq[2] + rq[3];
  }
}

// Fused prep: blocks [0,768) pack weights (float4-vectorized) + biases + zero S;
// blocks [768,1024) do the x transpose + LN1 column stats (old trx_stats).
__global__ __launch_bounds__(256) void prep_all(
    const float* __restrict__ tw, const float* __restrict__ pw,
    const float* __restrict__ c1, const float* __restrict__ c2,
    const float* __restrict__ tb, const float* __restrict__ pb,
    const float* __restrict__ x,
    __hip_bfloat16* __restrict__ Wb, float* __restrict__ bcat,
    float* __restrict__ S, __hip_bfloat16* __restrict__ xb,
    float* __restrict__ cxp, float* __restrict__ cx2p) {
  __shared__ float ts[128 * 49];
  __shared__ float ps[192], pq[192];
  if (blockIdx.x < 768) {
    int g = blockIdx.x * 256 + threadIdx.x;  // float4 index < 196608
    float4 v;
    if (g < 32768)       v = ((const float4*)tw)[g];
    else if (g < 65536)  v = ((const float4*)pw)[g - 32768];
    else if (g < 131072) v = ((const float4*)c1)[g - 65536];
    else                 v = ((const float4*)c2)[g - 131072];
    union { short4 s4; __hip_bfloat16 h[4]; } u;
    u.h[0] = __float2bfloat16(v.x);
    u.h[1] = __float2bfloat16(v.y);
    u.h[2] = __float2bfloat16(v.z);
    u.h[3] = __float2bfloat16(v.w);
    ((short4*)Wb)[g] = u.s4;
    if (g < 64)       ((float4*)bcat)[g] = ((const float4*)tb)[g];
    else if (g < 128) ((float4*)bcat)[g] = ((const float4*)pb)[g - 64];
    if (g < 768) ((float4*)S)[g] = make_float4(0.f, 0.f, 0.f, 0.f);
    return;
  }
  const int bb = blockIdx.x - 768;
  const int bx = bb & 3;       // c-chunk of 128
  const int n  = bb >> 2;
  const int t  = threadIdx.x;
  const float* src = x + (size_t)n * LNSZ + (size_t)bx * 128 * HW;
#pragma unroll
  for (int k = 0; k < 6; ++k) {
    int idx = t + k * 256;               // float4 index over 1536
    float4 v = ((const float4*)src)[idx];
    int c = idx / 12, sq = (idx % 12) * 4;
    float* d = ts + c * 49 + sq;
    d[0] = v.x; d[1] = v.y; d[2] = v.z; d[3] = v.w;
  }
  __syncthreads();
  if (t < 192) {
    int s = t % 48, q = t / 48;
    float sum = 0.f, sq2 = 0.f;
#pragma unroll
    for (int c = q * 32; c < q * 32 + 32; ++c) {
      float v = ts[c * 49 + s];
      sum += v; sq2 += v * v;
    }
    ps[t] = sum; pq[t] = sq2;
  }
  __hip_bfloat16* dst = xb + (size_t)n * LNSZ + bx * 128;
#pragma unroll
  for (int k = 0; k < 12; ++k) {
    int idx = t + k * 256;
    int s = idx >> 6, cp = idx & 63;
    __hip_bfloat162 p;
    p.x = __float2bfloat16(ts[(cp * 2) * 49 + s]);
    p.y = __float2bfloat16(ts[(cp * 2 + 1) * 49 + s]);
    *(__hip_bfloat162*)(dst + (size_t)s * 512 + cp * 2) = p;
  }
  __syncthreads();
  if (t < 48) {
    cxp[((size_t)n * 4 + bx) * 48 + t] = ps[t] + ps[48 + t] + ps[96 + t] + ps[144 + t];
    cx2p[((size_t)n * 4 + bx) * 48 + t] = pq[t] + pq[48 + t] + pq[96 + t] + pq[144 + t];
  }
}

// MFMA GEMM (per-sample), transposed bf16 output:
// outb[n][s][o] = bf16( sum_c Wb[o][c] * inb[n][s][c] + bias[o] ), opt relu.
// Grid (8 o-chunks of 64, 64 n), 256 thr; wave = 16 o x 48 s, depth-2 pipeline.
// If Pp != null, blocks with oc>=4 (phi rows) also emit the 2x2 pooled Pp tile.
__global__ __launch_bounds__(256) void gemm_bf16out(
    const __hip_bfloat16* __restrict__ Wb, const __hip_bfloat16* __restrict__ inb,
    const float* __restrict__ bias, __hip_bfloat16* __restrict__ outb, int relu,
    __hip_bfloat16* __restrict__ Pp) {
  const int oc = blockIdx.x, n = blockIdx.y;
  const int w = threadIdx.x >> 6, lane = threadIdx.x & 63;
  const int c16 = lane & 15, quad = lane >> 4;
  const int obase = oc * 64 + w * 16;

  const __hip_bfloat16* A0 = Wb + (size_t)(obase + c16) * 512 + quad * 8;
  const __hip_bfloat16* B0 = inb + (size_t)n * LNSZ + (size_t)c16 * 512 + quad * 8;

  floatx4 zero = {0.f, 0.f, 0.f, 0.f};
  floatx4 acc[3] = {zero, zero, zero};

  // depth-2 rotating fragment sets (phase A = k, phase B = k+32)
  bf16x8 aA  = *(const bf16x8*)(A0);
  bf16x8 bA0 = *(const bf16x8*)(B0);
  bf16x8 bA1 = *(const bf16x8*)(B0 + 16 * 512);
  bf16x8 bA2 = *(const bf16x8*)(B0 + 32 * 512);
  bf16x8 aB  = *(const bf16x8*)(A0 + 32);
  bf16x8 bB0 = *(const bf16x8*)(B0 + 32);
  bf16x8 bB1 = *(const bf16x8*)(B0 + 16 * 512 + 32);
  bf16x8 bB2 = *(const bf16x8*)(B0 + 32 * 512 + 32);
#pragma unroll 1
  for (int k = 0; k < 448; k += 64) {
    acc[0] = __builtin_amdgcn_mfma_f32_16x16x32_bf16(aA, bA0, acc[0], 0, 0, 0);
    acc[1] = __builtin_amdgcn_mfma_f32_16x16x32_bf16(aA, bA1, acc[1], 0, 0, 0);
    acc[2] = __builtin_amdgcn_mfma_f32_16x16x32_bf16(aA, bA2, acc[2], 0, 0, 0);
    aA  = *(const bf16x8*)(A0 + k + 64);
    bA0 = *(const bf16x8*)(B0 + k + 64);
    bA1 = *(const bf16x8*)(B0 + 16 * 512 + k + 64);
    bA2 = *(const bf16x8*)(B0 + 32 * 512 + k + 64);
    acc[0] = __builtin_amdgcn_mfma_f32_16x16x32_bf16(aB, bB0, acc[0], 0, 0, 0);
    acc[1] = __builtin_amdgcn_mfma_f32_16x16x32_bf16(aB, bB1, acc[1], 0, 0, 0);
    acc[2] = __builtin_amdgcn_mfma_f32_16x16x32_bf16(aB, bB2, acc[2], 0, 0, 0);
    aB  = *(const bf16x8*)(A0 + k + 96);
    bB0 = *(const bf16x8*)(B0 + k + 96);
    bB1 = *(const bf16x8*)(B0 + 16 * 512 + k + 96);
    bB2 = *(const bf16x8*)(B0 + 32 * 512 + k + 96);
  }
  acc[0] = __builtin_amdgcn_mfma_f32_16x16x32_bf16(aA, bA0, acc[0], 0, 0, 0);
  acc[1] = __builtin_amdgcn_mfma_f32_16x16x32_bf16(aA, bA1, acc[1], 0, 0, 0);
  acc[2] = __builtin_amdgcn_mfma_f32_16x16x32_bf16(aA, bA2, acc[2], 0, 0, 0);
  acc[0] = __builtin_amdgcn_mfma_f32_16x16x32_bf16(aB, bB0, acc[0], 0, 0, 0);
  acc[1] = __builtin_amdgcn_mfma_f32_16x16x32_bf16(aB, bB1, acc[1], 0, 0, 0);
  acc[2] = __builtin_amdgcn_mfma_f32_16x16x32_bf16(aB, bB2, acc[2], 0, 0, 0);

  __shared__ float pt[64 * 49];   // fp32 phi tile for fused pooling
  const int do_pp = (Pp != nullptr) && (oc >= 4);
  const int o0 = obase + quad * 4;
  float bv[4];
#pragma unroll
  for (int r = 0; r < 4; ++r) bv[r] = bias ? bias[o0 + r] : 0.f;
  __hip_bfloat16* on = outb + (size_t)n * LNSZ;
#pragma unroll
  for (int j = 0; j < 3; ++j) {
    const int s = j * 16 + c16;
    union { short4 s4; __hip_bfloat16 h[4]; } u;
#pragma unroll
    for (int r = 0; r < 4; ++r) {
      float vv = acc[j][r] + bv[r];
      if (relu) vv = fmaxf(vv, 0.f);
      u.h[r] = __float2bfloat16(vv);
      if (do_pp) pt[(w * 16 + quad * 4 + r) * 49 + s] = vv;
    }
    *(short4*)(on + (size_t)s * 512 + o0) = u.s4;
  }
  if (do_pp) {
    __syncthreads();
    // 12 m x 64 local-ci pooled outputs (max commutes with monotone bf16 round)
#pragma unroll
    for (int rep = 0; rep < 3; ++rep) {
      int idx = threadIdx.x + rep * 256;
      int m = idx >> 6, cil = idx & 63;
      int sb = (m >> 1) * 8 + (m & 1) * 2;
      const float* pr = pt + cil * 49;
      float mx = fmaxf(fmaxf(pr[sb], pr[sb + 1]), fmaxf(pr[sb + 4], pr[sb + 5]));
      Pp[((size_t)(n * 12 + m) << 8) + (oc - 4) * 64 + cil] = __float2bfloat16(mx);
    }
  }
}

// Score GEMM with fused pool-max + query-sum:
// S[row] += (1/12) * sum_{i in block} max_{m<12} (Th[row] . Pp[i*12+m])
// Grid (16 col-blocks of 48, 48 row-blocks of 64); wave = 16 rows x 48 cols.
__global__ __launch_bounds__(256) void dgemm_fused(
    const __hip_bfloat16* __restrict__ A, const __hip_bfloat16* __restrict__ B,
    float* __restrict__ S) {
  const int bn = blockIdx.x * 48;
  const int w = threadIdx.x >> 6, lane = threadIdx.x & 63;
  const int c16 = lane & 15, quad = lane >> 4;
  const int bm = blockIdx.y * 64 + w * 16;

  const __hip_bfloat16* A0 = A + (size_t)(bm + c16) * 512 + quad * 8;
  const __hip_bfloat16* Bp = B + (size_t)(bn + c16) * 256 + quad * 8;

  floatx4 zero = {0.f, 0.f, 0.f, 0.f};
  floatx4 acc[3] = {zero, zero, zero};

  bf16x8 aA  = *(const bf16x8*)(A0);
  bf16x8 bA0 = *(const bf16x8*)(Bp);
  bf16x8 bA1 = *(const bf16x8*)(Bp + 16 * 256);
  bf16x8 bA2 = *(const bf16x8*)(Bp + 32 * 256);
  bf16x8 aB  = *(const bf16x8*)(A0 + 32);
  bf16x8 bB0 = *(const bf16x8*)(Bp + 32);
  bf16x8 bB1 = *(const bf16x8*)(Bp + 16 * 256 + 32);
  bf16x8 bB2 = *(const bf16x8*)(Bp + 32 * 256 + 32);
#pragma unroll 1
  for (int k = 0; k < 192; k += 64) {
    acc[0] = __builtin_amdgcn_mfma_f32_16x16x32_bf16(aA, bA0, acc[0], 0, 0, 0);
    acc[1] = __builtin_amdgcn_mfma_f32_16x16x32_bf16(aA, bA1, acc[1], 0, 0, 0);
    acc[2] = __builtin_amdgcn_mfma_f32_16x16x32_bf16(aA, bA2, acc[2], 0, 0, 0);
    aA  = *(const bf16x8*)(A0 + k + 64);
    bA0 = *(const bf16x8*)(Bp + k + 64);
    bA1 = *(const bf16x8*)(Bp + 16 * 256 + k + 64);
    bA2 = *(const bf16x8*)(Bp + 32 * 256 + k + 64);
    acc[0] = __builtin_amdgcn_mfma_f32_16x16x32_bf16(aB, bB0, acc[0], 0, 0, 0);
    acc[1] = __builtin_amdgcn_mfma_f32_16x16x32_bf16(aB, bB1, acc[1], 0, 0, 0);
    acc[2] = __builtin_amdgcn_mfma_f32_16x16x32_bf16(aB, bB2, acc[2], 0, 0, 0);
    aB  = *(const bf16x8*)(A0 + k + 96);
    bB0 = *(const bf16x8*)(Bp + k + 96);
    bB1 = *(const bf16x8*)(Bp + 16 * 256 + k + 96);
    bB2 = *(const bf16x8*)(Bp + 32 * 256 + k + 96);
  }
  acc[0] = __builtin_amdgcn_mfma_f32_16x16x32_bf16(aA, bA0, acc[0], 0, 0, 0);
  acc[1] = __builtin_amdgcn_mfma_f32_16x16x32_bf16(aA, bA1, acc[1], 0, 0, 0);
  acc[2] = __builtin_amdgcn_mfma_f32_16x16x32_bf16(aA, bA2, acc[2], 0, 0, 0);
  acc[0] = __builtin_amdgcn_mfma_f32_16x16x32_bf16(aB, bB0, acc[0], 0, 0, 0);
  acc[1] = __builtin_amdgcn_mfma_f32_16x16x32_bf16(aB, bB1, acc[1], 0, 0, 0);
  acc[2] = __builtin_amdgcn_mfma_f32_16x16x32_bf16(aB, bB2, acc[2], 0, 0, 0);

  // LDS transpose per wave: red[w][col*17 + row], 16 rows x 48 cols
  __shared__ float red[4 * 48 * 17];
  float* rw = red + w * (48 * 17);
#pragma unroll
  for (int j = 0; j < 3; ++j)
#pragma unroll
    for (int r = 0; r < 4; ++r)
      rw[(j * 16 + c16) * 17 + (quad * 4 + r)] = acc[j][r];
  __syncthreads();
  if (lane < 16) {
    float sum = 0.f;
#pragma unroll
    for (int grp = 0; grp < 4; ++grp) {
      float mx = rw[(grp * 12) * 17 + lane];
#pragma unroll
      for (int m = 1; m < 12; ++m)
        mx = fmaxf(mx, rw[(grp * 12 + m) * 17 + lane]);
      sum += mx;
    }
    atomicAdd(&S[bm + lane], sum * (1.0f / 12.0f));
  }
}

// y = LN1(x*(1+S)) -> fp32 [c][s] AND bf16 [s][c] (fused transpose).
// LN1 stats (mu/rstd) computed in-block from S + colsum partials (fused finish).
__global__ __launch_bounds__(256) void ln1_norm_tr(
    const float* __restrict__ x, const float* __restrict__ S,
    const float* __restrict__ cxp, const float* __restrict__ cx2p,
    const float* __restrict__ g, const float* __restrict__ b,
    float* __restrict__ y, __hip_bfloat16* __restrict__ yb) {
  const int bx = blockIdx.x, n = blockIdx.y, t = threadIdx.x;
  __shared__ float ts[128 * 49];
  __shared__ float sS[HW];
  __shared__ float sstat[2];
  if (t < HW) sS[t] = 1.0f + S[n * HW + t];
  if (t < 64) {
    float sum = 0.f, sq = 0.f;
    if (t < 48) {
      float a = 1.0f + S[n * HW + t];
      float c1 = 0.f, c2 = 0.f;
#pragma unroll
      for (int ch = 0; ch < 4; ++ch) {
        c1 += cxp[((size_t)n * 4 + ch) * 48 + t];
        c2 += cx2p[((size_t)n * 4 + ch) * 48 + t];
      }
      sum = a * c1;
      sq = a * a * c2;
    }
#pragma unroll
    for (int off = 32; off > 0; off >>= 1) {
      sum += __shfl_down(sum, off, 64);
      sq  += __shfl_down(sq, off, 64);
    }
    if (t == 0) {
      float mu = sum * (1.0f / LNSZ);
      float var = sq * (1.0f / LNSZ) - mu * mu;
      sstat[0] = mu;
      sstat[1] = 1.0f / sqrtf(var + 1e-5f);
    }
  }
  __syncthreads();
  const float mu = sstat[0], rstd = sstat[1];
  const size_t chunk = (size_t)bx * 6144;
  const float* xn = x + (size_t)n * LNSZ + chunk;
  float* yn = y + (size_t)n * LNSZ + chunk;
  const float* gp = g + chunk;
  const float* bp = b + chunk;
#pragma unroll
  for (int k = 0; k < 6; ++k) {
    int idx = t + k * 256;
    int c = idx / 12, sq0 = (idx % 12) * 4;
    float4 xv = ((const float4*)xn)[idx];
    float4 gv = ((const float4*)gp)[idx];
    float4 bv = ((const float4*)bp)[idx];
    float4 o;
    o.x = (xv.x * sS[sq0]     - mu) * rstd * gv.x + bv.x;
    o.y = (xv.y * sS[sq0 + 1] - mu) * rstd * gv.y + bv.y;
    o.z = (xv.z * sS[sq0 + 2] - mu) * rstd * gv.z + bv.z;
    o.w = (xv.w * sS[sq0 + 3] - mu) * rstd * gv.w + bv.w;
    ((float4*)yn)[idx] = o;
    float* d = ts + c * 49 + sq0;
    d[0] = o.x; d[1] = o.y; d[2] = o.z; d[3] = o.w;
  }
  __syncthreads();
  __hip_bfloat16* dst = yb + (size_t)n * LNSZ + bx * 128;
#pragma unroll
  for (int k = 0; k < 12; ++k) {
    int idx = t + k * 256;
    int s = idx >> 6, cp = idx & 63;
    __hip_bfloat162 p;
    p.x = __float2bfloat16(ts[(cp * 2) * 49 + s]);
    p.y = __float2bfloat16(ts[(cp * 2 + 1) * 49 + s]);
    *(__hip_bfloat162*)(dst + (size_t)s * 512 + cp * 2) = p;
  }
}

// conv2 with fused residual + LN2 stats: v = y + Wc2@ub; stats2[n][oc]={S,S2}
// Grid (8 o-chunks of 64, 64 n); wave = 16 o x 48 s, depth-2 pipeline.
__global__ __launch_bounds__(256) void conv2_fused(
    const __hip_bfloat16* __restrict__ Wb, const __hip_bfloat16* __restrict__ inb,
    const float* __restrict__ y, float* __restrict__ v,
    float2* __restrict__ stats2) {
  const int oc = blockIdx.x, n = blockIdx.y;
  const int w = threadIdx.x >> 6, lane = threadIdx.x & 63;
  const int c16 = lane & 15, quad = lane >> 4;
  const int obase = oc * 64 + w * 16;

  const __hip_bfloat16* A0 = Wb + (size_t)(obase + c16) * 512 + quad * 8;
  const __hip_bfloat16* B0 = inb + (size_t)n * LNSZ + (size_t)c16 * 512 + quad * 8;

  floatx4 zero = {0.f, 0.f, 0.f, 0.f};
  floatx4 acc[3] = {zero, zero, zero};

  bf16x8 aA  = *(const bf16x8*)(A0);
  bf16x8 bA0 = *(const bf16x8*)(B0);
  bf16x8 bA1 = *(const bf16x8*)(B0 + 16 * 512);
  bf16x8 bA2 = *(const bf16x8*)(B0 + 32 * 512);
  bf16x8 aB  = *(const bf16x8*)(A0 + 32);
  bf16x8 bB0 = *(const bf16x8*)(B0 + 32);
  bf16x8 bB1 = *(const bf16x8*)(B0 + 16 * 512 + 32);
  bf16x8 bB2 = *(const bf16x8*)(B0 + 32 * 512 + 32);
#pragma unroll 1
  for (int k = 0; k < 448; k += 64) {
    acc[0] = __builtin_amdgcn_mfma_f32_16x16x32_bf16(aA, bA0, acc[0], 0, 0, 0);
    acc[1] = __builtin_amdgcn_mfma_f32_16x16x32_bf16(aA, bA1, acc[1], 0, 0, 0);
    acc[2] = __builtin_amdgcn_mfma_f32_16x16x32_bf16(aA, bA2, acc[2], 0, 0, 0);
    aA  = *(const bf16x8*)(A0 + k + 64);
    bA0 = *(const bf16x8*)(B0 + k + 64);
    bA1 = *(const bf16x8*)(B0 + 16 * 512 + k + 64);
    bA2 = *(const bf16x8*)(B0 + 32 * 512 + k + 64);
    acc[0] = __builtin_amdgcn_mfma_f32_16x16x32_bf16(aB, bB0, acc[0], 0, 0, 0);
    acc[1] = __builtin_amdgcn_mfma_f32_16x16x32_bf16(aB, bB1, acc[1], 0, 0, 0);
    acc[2] = __builtin_amdgcn_mfma_f32_16x16x32_bf16(aB, bB2, acc[2], 0, 0, 0);
    aB  = *(const bf16x8*)(A0 + k + 96);
    bB0 = *(const bf16x8*)(B0 + k + 96);
    bB1 = *(const bf16x8*)(B0 + 16 * 512 + k + 96);
    bB2 = *(const bf16x8*)(B0 + 32 * 512 + k + 96);
  }
  acc[0] = __builtin_amdgcn_mfma_f32_16x16x32_bf16(aA, bA0, acc[0], 0, 0, 0);
  acc[1] = __builtin_amdgcn_mfma_f32_16x16x32_bf16(aA, bA1, acc[1], 0, 0, 0);
  acc[2] = __builtin_amdgcn_mfma_f32_16x16x32_bf16(aA, bA2, acc[2], 0, 0, 0);
  acc[0] = __builtin_amdgcn_mfma_f32_16x16x32_bf16(aB, bB0, acc[0], 0, 0, 0);
  acc[1] = __builtin_amdgcn_mfma_f32_16x16x32_bf16(aB, bB1, acc[1], 0, 0, 0);
  acc[2] = __builtin_amdgcn_mfma_f32_16x16x32_bf16(aB, bB2, acc[2], 0, 0, 0);

  const float* yn = y + (size_t)n * LNSZ;
  float* vn = v + (size_t)n * LNSZ;
  float sum = 0.f, sq = 0.f;
  const int o0 = obase + quad * 4;
#pragma unroll
  for (int r = 0; r < 4; ++r) {
    const int o = o0 + r;
#pragma unroll
    for (int j = 0; j < 3; ++j) {
      const int s = j * 16 + c16;
      float val = acc[j][r] + yn[(size_t)o * HW + s];
      vn[(size_t)o * HW + s] = val;
      sum += val;
      sq += val * val;
    }
  }
  block_reduce2(sum, sq);
  if (threadIdx.x == 0) stats2[n * 8 + oc] = make_float2(sum, sq);
}

__global__ __launch_bounds__(256) void ln2_norm(
    const float* __restrict__ v, const float2* __restrict__ stats2,
    const float* __restrict__ g2, const float* __restrict__ b2,
    float* __restrict__ out) {
  const int bx = blockIdx.x, n = blockIdx.y, t = threadIdx.x;
  __shared__ float smu, srstd;
  if (t == 0) {
    float s1 = 0.f, s2 = 0.f;
#pragma unroll
    for (int k = 0; k < 8; ++k) {
      float2 p = stats2[n * 8 + k];
      s1 += p.x; s2 += p.y;
    }
    float mu = s1 * (1.0f / LNSZ);
    float var = s2 * (1.0f / LNSZ) - mu * mu;
    smu = mu;
    srstd = 1.0f / sqrtf(var + 1e-5f);
  }
  __syncthreads();
  const float mu = smu, rstd = srstd;
  const size_t chunk = (size_t)bx * 6144;
  const float* vn = v + (size_t)n * LNSZ + chunk;
  float* on = out + (size_t)n * LNSZ + chunk;
  const float* gp = g2 + chunk;
  const float* bp = b2 + chunk;
#pragma unroll
  for (int k = 0; k < 6; ++k) {
    int idx = t + k * 256;
    float4 vv = ((const float4*)vn)[idx];
    float4 gv = ((const float4*)gp)[idx];
    float4 bv = ((const float4*)bp)[idx];
    float4 o;
    o.x = (vv.x - mu) * rstd * gv.x + bv.x;
    o.y = (vv.y - mu) * rstd * gv.y + bv.y;
    o.z = (vv.z - mu) * rstd * gv.z + bv.z;
    o.w = (vv.w - mu) * rstd * gv.w + bv.w;
    ((float4*)on)[idx] = o;
  }
}

extern "C" void kernel_launch(void* const* d_in, const int* in_sizes, int n_in,
                              void* d_out, int out_size, void* d_ws, size_t ws_size,
                              hipStream_t stream) {
  const float* x   = (const float*)d_in[0];
  const float* tw  = (const float*)d_in[1];
  const float* tb  = (const float*)d_in[2];
  const float* pw  = (const float*)d_in[3];
  const float* pb  = (const float*)d_in[4];
  const float* c1w = (const float*)d_in[5];
  const float* c2w = (const float*)d_in[6];
  const float* g1  = (const float*)d_in[7];
  const float* b1  = (const float*)d_in[8];
  const float* g2  = (const float*)d_in[9];
  const float* b2  = (const float*)d_in[10];

  float* ws = (float*)d_ws;
  __hip_bfloat16* Wb = (__hip_bfloat16*)(ws + WB_OFF);
  float* bcat        = ws + BC_OFF;
  float* S           = ws + S_OFF;
  float* cxp         = ws + CXP_OFF;
  float* cx2p        = ws + CX2_OFF;
  __hip_bfloat16* xb = (__hip_bfloat16*)(ws + XB_OFF);
  __hip_bfloat16* tp = (__hip_bfloat16*)(ws + TP_OFF);
  __hip_bfloat16* yb = (__hip_bfloat16*)(ws + YB_OFF);
  __hip_bfloat16* ub = (__hip_bfloat16*)(ws + UB_OFF);
  __hip_bfloat16* Pp = (__hip_bfloat16*)(ws + PP_OFF);
  float2* st2        = (float2*)(ws + ST2_OFF);
  float* y           = ws + YY_OFF;
  float* v           = ws + VV_OFF;
  float* out         = (float*)d_out;

  // weights pack + bias cat + S zero (blocks 0..767) and x transpose + LN1
  // column stats (blocks 768..1023), one launch
  prep_all<<<1024, 256, 0, stream>>>(tw, pw, c1w, c2w, tb, pb, x,
                                     Wb, bcat, S, xb, cxp, cx2p);
  // theta+phi projection + fused 2x2 pool -> tp and Pp
  gemm_bf16out<<<dim3(8, NN), 256, 0, stream>>>(Wb, xb, bcat, tp, 0, Pp);
  // score GEMM + pool-max + query-sum -> S (atomic)
  dgemm_fused<<<dim3(16, 48), 256, 0, stream>>>(tp, Pp, S);
  // LN1 stats (fused) + apply -> y fp32 + yb bf16 (fused transpose)
  ln1_norm_tr<<<dim3(4, NN), 256, 0, stream>>>(x, S, cxp, cx2p, g1, b1, y, yb);
  // conv1 + relu -> ub bf16 [s][c]
  gemm_bf16out<<<dim3(8, NN), 256, 0, stream>>>(Wb + 512 * 512, yb, nullptr, ub, 1,
                                                nullptr);
  // conv2 + residual + LN2 stats
  conv2_fused<<<dim3(8, NN), 256, 0, stream>>>(Wb + 1024 * 512, ub, y, v, st2);
  ln2_norm<<<dim3(4, NN), 256, 0, stream>>>(v, st2, g2, b2, out);
}

// Round 2
// 135.693 us; speedup vs baseline: 1.1332x; 1.1332x over previous
//
#include <hip/hip_runtime.h>
#include <hip/hip_bf16.h>

#define NN 64
#define CC 512
#define HW 48
#define LNSZ (CC * HW)   // 24576 per sample

typedef __attribute__((ext_vector_type(8))) short bf16x8;  // 8 bf16 (4 VGPRs)
typedef __attribute__((ext_vector_type(4))) float floatx4;

// ---- workspace layout (float offsets) ----
static const size_t WB_OFF   = 0;        // 1536x512 bf16 = 393216 float-slots
static const size_t BC_OFF   = 393216;   // 512 fp32 biases (theta ++ phi)
static const size_t S_OFF    = 393728;   // 3072 fp32 (attention scale, atomic)
static const size_t CXP_OFF  = 396928;   // [64][4][48] colsum partials
static const size_t CX2_OFF  = 409216;   // [64][4][48] colsumsq partials
static const size_t ST2_OFF  = 421504;   // [64][4] float2 ln2 stats
static const size_t XB_OFF   = 422016;   // [64][48][512] bf16 = 786432 slots
static const size_t TP_OFF   = 1208448;  // ThPhi bf16 [64][48][512]
static const size_t YB_OFF   = 1994880;  // yb bf16 [64][48][512]
static const size_t UB_OFF   = 2781312;  // ub bf16 [64][48][512]
static const size_t PP_OFF   = 3567744;  // Pp bf16 [768][256] = 98304 slots
static const size_t YY_OFF   = 3666048;  // y fp32 [64][512][48]
static const size_t VV_OFF   = 5238912;  // v fp32 [64][512][48]

// block-level {sum, sumsq} reduction; valid result in thread 0
__device__ __forceinline__ void block_reduce2(float& sum, float& sq) {
  const int lane = threadIdx.x & 63, w = threadIdx.x >> 6;
#pragma unroll
  for (int off = 32; off > 0; off >>= 1) {
    sum += __shfl_down(sum, off, 64);
    sq  += __shfl_down(sq, off, 64);
  }
  __shared__ float rs[4], rq[4];
  if (lane == 0) { rs[w] = sum; rq[w] = sq; }
  __syncthreads();
  if (threadIdx.x == 0) {
    sum = rs[0] + rs[1] + rs[2] + rs[3];
    sq  = rq[0] + rq[1] + rq[2] + rq[3];
  }
}

// Fused prep: blocks [0,768) pack weights (float4-vectorized) + biases + zero S;
// blocks [768,1024) do the x transpose + LN1 column stats.
__global__ __launch_bounds__(256) void prep_all(
    const float* __restrict__ tw, const float* __restrict__ pw,
    const float* __restrict__ c1, const float* __restrict__ c2,
    const float* __restrict__ tb, const float* __restrict__ pb,
    const float* __restrict__ x,
    __hip_bfloat16* __restrict__ Wb, float* __restrict__ bcat,
    float* __restrict__ S, __hip_bfloat16* __restrict__ xb,
    float* __restrict__ cxp, float* __restrict__ cx2p) {
  __shared__ float ts[128 * 49];
  __shared__ float ps[192], pq[192];
  if (blockIdx.x < 768) {
    int g = blockIdx.x * 256 + threadIdx.x;  // float4 index < 196608
    float4 v;
    if (g < 32768)       v = ((const float4*)tw)[g];
    else if (g < 65536)  v = ((const float4*)pw)[g - 32768];
    else if (g < 131072) v = ((const float4*)c1)[g - 65536];
    else                 v = ((const float4*)c2)[g - 131072];
    union { short4 s4; __hip_bfloat16 h[4]; } u;
    u.h[0] = __float2bfloat16(v.x);
    u.h[1] = __float2bfloat16(v.y);
    u.h[2] = __float2bfloat16(v.z);
    u.h[3] = __float2bfloat16(v.w);
    ((short4*)Wb)[g] = u.s4;
    if (g < 64)       ((float4*)bcat)[g] = ((const float4*)tb)[g];
    else if (g < 128) ((float4*)bcat)[g] = ((const float4*)pb)[g - 64];
    if (g < 768) ((float4*)S)[g] = make_float4(0.f, 0.f, 0.f, 0.f);
    return;
  }
  const int bb = blockIdx.x - 768;
  const int bx = bb & 3;       // c-chunk of 128
  const int n  = bb >> 2;
  const int t  = threadIdx.x;
  const float* src = x + (size_t)n * LNSZ + (size_t)bx * 128 * HW;
#pragma unroll
  for (int k = 0; k < 6; ++k) {
    int idx = t + k * 256;               // float4 index over 1536
    float4 v = ((const float4*)src)[idx];
    int c = idx / 12, sq = (idx % 12) * 4;
    float* d = ts + c * 49 + sq;
    d[0] = v.x; d[1] = v.y; d[2] = v.z; d[3] = v.w;
  }
  __syncthreads();
  if (t < 192) {
    int s = t % 48, q = t / 48;
    float sum = 0.f, sq2 = 0.f;
#pragma unroll
    for (int c = q * 32; c < q * 32 + 32; ++c) {
      float v = ts[c * 49 + s];
      sum += v; sq2 += v * v;
    }
    ps[t] = sum; pq[t] = sq2;
  }
  __hip_bfloat16* dst = xb + (size_t)n * LNSZ + bx * 128;
#pragma unroll
  for (int k = 0; k < 12; ++k) {
    int idx = t + k * 256;
    int s = idx >> 6, cp = idx & 63;
    __hip_bfloat162 p;
    p.x = __float2bfloat16(ts[(cp * 2) * 49 + s]);
    p.y = __float2bfloat16(ts[(cp * 2 + 1) * 49 + s]);
    *(__hip_bfloat162*)(dst + (size_t)s * 512 + cp * 2) = p;
  }
  __syncthreads();
  if (t < 48) {
    cxp[((size_t)n * 4 + bx) * 48 + t] = ps[t] + ps[48 + t] + ps[96 + t] + ps[144 + t];
    cx2p[((size_t)n * 4 + bx) * 48 + t] = pq[t] + pq[48 + t] + pq[96 + t] + pq[144 + t];
  }
}

// MFMA GEMM (per-sample), transposed bf16 output (round-0 geometry):
// outb[n][s][o] = bf16( sum_c Wb[o][c] * inb[n][s][c] + bias[o] ), opt relu.
// Grid (4 o-chunks of 128, 64 n), 256 thr; wave = 32 o x 48 s.
// If Pp != null, blocks with oc>=2 (phi rows) also emit the 2x2 pooled Pp tile
// from the fp32 pre-round values (max commutes with monotone bf16 rounding).
__global__ __launch_bounds__(256) void gemm_bf16out(
    const __hip_bfloat16* __restrict__ Wb, const __hip_bfloat16* __restrict__ inb,
    const float* __restrict__ bias, __hip_bfloat16* __restrict__ outb, int relu,
    __hip_bfloat16* __restrict__ Pp) {
  const int oc = blockIdx.x, n = blockIdx.y;
  const int w = threadIdx.x >> 6, lane = threadIdx.x & 63;
  const int c16 = lane & 15, quad = lane >> 4;
  const int obase = oc * 128 + w * 32;

  const __hip_bfloat16* A0 = Wb + (size_t)(obase + c16) * 512 + quad * 8;
  const __hip_bfloat16* A1 = A0 + 16 * 512;
  const __hip_bfloat16* B0 = inb + (size_t)n * LNSZ + (size_t)c16 * 512 + quad * 8;

  floatx4 zero = {0.f, 0.f, 0.f, 0.f};
  floatx4 acc[2][3];
#pragma unroll
  for (int i = 0; i < 2; ++i)
#pragma unroll
    for (int j = 0; j < 3; ++j) acc[i][j] = zero;

  bf16x8 a[2], b[3];
  a[0] = *(const bf16x8*)(A0);
  a[1] = *(const bf16x8*)(A1);
  b[0] = *(const bf16x8*)(B0);
  b[1] = *(const bf16x8*)(B0 + 16 * 512);
  b[2] = *(const bf16x8*)(B0 + 32 * 512);

  for (int k = 0; k < 480; k += 32) {
    bf16x8 an[2], bn[3];
    const int k2 = k + 32;
    an[0] = *(const bf16x8*)(A0 + k2);
    an[1] = *(const bf16x8*)(A1 + k2);
    bn[0] = *(const bf16x8*)(B0 + k2);
    bn[1] = *(const bf16x8*)(B0 + 16 * 512 + k2);
    bn[2] = *(const bf16x8*)(B0 + 32 * 512 + k2);
#pragma unroll
    for (int i = 0; i < 2; ++i)
#pragma unroll
      for (int j = 0; j < 3; ++j)
        acc[i][j] = __builtin_amdgcn_mfma_f32_16x16x32_bf16(a[i], b[j],
                                                            acc[i][j], 0, 0, 0);
    a[0] = an[0]; a[1] = an[1];
    b[0] = bn[0]; b[1] = bn[1]; b[2] = bn[2];
  }
#pragma unroll
  for (int i = 0; i < 2; ++i)
#pragma unroll
    for (int j = 0; j < 3; ++j)
      acc[i][j] = __builtin_amdgcn_mfma_f32_16x16x32_bf16(a[i], b[j],
                                                          acc[i][j], 0, 0, 0);

  __shared__ float pt[128 * 49];   // fp32 phi tile for fused pooling
  const int do_pp = (Pp != nullptr) && (oc >= 2);

  __hip_bfloat16* on = outb + (size_t)n * LNSZ;
#pragma unroll
  for (int i = 0; i < 2; ++i) {
    const int o0 = obase + i * 16 + quad * 4;
    float bv[4];
#pragma unroll
    for (int r = 0; r < 4; ++r) bv[r] = bias ? bias[o0 + r] : 0.f;
#pragma unroll
    for (int j = 0; j < 3; ++j) {
      const int s = j * 16 + c16;
      union { short4 s4; __hip_bfloat16 h[4]; } u;
#pragma unroll
      for (int r = 0; r < 4; ++r) {
        float v = acc[i][j][r] + bv[r];
        if (relu) v = fmaxf(v, 0.f);
        u.h[r] = __float2bfloat16(v);
        if (do_pp) pt[(w * 32 + i * 16 + quad * 4 + r) * 49 + s] = v;
      }
      *(short4*)(on + (size_t)s * 512 + o0) = u.s4;
    }
  }
  if (do_pp) {
    __syncthreads();
    // 12 m x 128 local-ci pooled outputs
#pragma unroll
    for (int rep = 0; rep < 6; ++rep) {
      int idx = threadIdx.x + rep * 256;     // < 1536
      int m = idx >> 7, cil = idx & 127;
      int sb = (m >> 1) * 8 + (m & 1) * 2;
      const float* pr = pt + cil * 49;
      float mx = fmaxf(fmaxf(pr[sb], pr[sb + 1]), fmaxf(pr[sb + 4], pr[sb + 5]));
      Pp[((size_t)(n * 12 + m) << 8) + (oc - 2) * 128 + cil] = __float2bfloat16(mx);
    }
  }
}

// Score GEMM with fused pool-max + query-sum (round-0 geometry):
// S[row] += (1/12) * sum_{i in block} max_{m<12} (Th[row] . Pp[i*12+m])
// Grid (16 col-blocks of 48, 24 row-blocks of 128); wave = 32 rows x 48 cols.
__global__ __launch_bounds__(256) void dgemm_fused(
    const __hip_bfloat16* __restrict__ A, const __hip_bfloat16* __restrict__ B,
    float* __restrict__ S) {
  const int bn = blockIdx.x * 48;
  const int w = threadIdx.x >> 6, lane = threadIdx.x & 63;
  const int c16 = lane & 15, quad = lane >> 4;
  const int bm = blockIdx.y * 128 + w * 32;

  const __hip_bfloat16* A0 = A + (size_t)(bm + c16) * 512 + quad * 8;
  const __hip_bfloat16* A1 = A0 + 16 * 512;
  const __hip_bfloat16* Bp = B + (size_t)(bn + c16) * 256 + quad * 8;

  floatx4 zero = {0.f, 0.f, 0.f, 0.f};
  floatx4 acc[2][3];
#pragma unroll
  for (int i = 0; i < 2; ++i)
#pragma unroll
    for (int j = 0; j < 3; ++j) acc[i][j] = zero;

#pragma unroll 2
  for (int k = 0; k < 256; k += 32) {
    bf16x8 a0 = *(const bf16x8*)(A0 + k);
    bf16x8 a1 = *(const bf16x8*)(A1 + k);
    bf16x8 b0 = *(const bf16x8*)(Bp + k);
    bf16x8 b1 = *(const bf16x8*)(Bp + 16 * 256 + k);
    bf16x8 b2 = *(const bf16x8*)(Bp + 32 * 256 + k);
    acc[0][0] = __builtin_amdgcn_mfma_f32_16x16x32_bf16(a0, b0, acc[0][0], 0, 0, 0);
    acc[0][1] = __builtin_amdgcn_mfma_f32_16x16x32_bf16(a0, b1, acc[0][1], 0, 0, 0);
    acc[0][2] = __builtin_amdgcn_mfma_f32_16x16x32_bf16(a0, b2, acc[0][2], 0, 0, 0);
    acc[1][0] = __builtin_amdgcn_mfma_f32_16x16x32_bf16(a1, b0, acc[1][0], 0, 0, 0);
    acc[1][1] = __builtin_amdgcn_mfma_f32_16x16x32_bf16(a1, b1, acc[1][1], 0, 0, 0);
    acc[1][2] = __builtin_amdgcn_mfma_f32_16x16x32_bf16(a1, b2, acc[1][2], 0, 0, 0);
  }

  // LDS transpose: red[w][col_local*33 + row_local]
  __shared__ float red[4 * 48 * 33];
  float* rw = red + w * (48 * 33);
#pragma unroll
  for (int i = 0; i < 2; ++i)
#pragma unroll
    for (int j = 0; j < 3; ++j)
#pragma unroll
      for (int r = 0; r < 4; ++r)
        rw[(j * 16 + c16) * 33 + (i * 16 + quad * 4 + r)] = acc[i][j][r];
  __syncthreads();
  if (lane < 32) {
    float sum = 0.f;
#pragma unroll
    for (int grp = 0; grp < 4; ++grp) {
      float mx = rw[(grp * 12) * 33 + lane];
#pragma unroll
      for (int m = 1; m < 12; ++m)
        mx = fmaxf(mx, rw[(grp * 12 + m) * 33 + lane]);
      sum += mx;
    }
    atomicAdd(&S[bm + lane], sum * (1.0f / 12.0f));
  }
}

// y = LN1(x*(1+S)) -> fp32 [c][s] AND bf16 [s][c] (fused transpose).
// LN1 stats (mu/rstd) computed in-block from S + colsum partials (fused finish).
__global__ __launch_bounds__(256) void ln1_norm_tr(
    const float* __restrict__ x, const float* __restrict__ S,
    const float* __restrict__ cxp, const float* __restrict__ cx2p,
    const float* __restrict__ g, const float* __restrict__ b,
    float* __restrict__ y, __hip_bfloat16* __restrict__ yb) {
  const int bx = blockIdx.x, n = blockIdx.y, t = threadIdx.x;
  __shared__ float ts[128 * 49];
  __shared__ float sS[HW];
  __shared__ float sstat[2];
  if (t < HW) sS[t] = 1.0f + S[n * HW + t];
  if (t < 64) {
    float sum = 0.f, sq = 0.f;
    if (t < 48) {
      float a = 1.0f + S[n * HW + t];
      float c1 = 0.f, c2 = 0.f;
#pragma unroll
      for (int ch = 0; ch < 4; ++ch) {
        c1 += cxp[((size_t)n * 4 + ch) * 48 + t];
        c2 += cx2p[((size_t)n * 4 + ch) * 48 + t];
      }
      sum = a * c1;
      sq = a * a * c2;
    }
#pragma unroll
    for (int off = 32; off > 0; off >>= 1) {
      sum += __shfl_down(sum, off, 64);
      sq  += __shfl_down(sq, off, 64);
    }
    if (t == 0) {
      float mu = sum * (1.0f / LNSZ);
      float var = sq * (1.0f / LNSZ) - mu * mu;
      sstat[0] = mu;
      sstat[1] = 1.0f / sqrtf(var + 1e-5f);
    }
  }
  __syncthreads();
  const float mu = sstat[0], rstd = sstat[1];
  const size_t chunk = (size_t)bx * 6144;
  const float* xn = x + (size_t)n * LNSZ + chunk;
  float* yn = y + (size_t)n * LNSZ + chunk;
  const float* gp = g + chunk;
  const float* bp = b + chunk;
#pragma unroll
  for (int k = 0; k < 6; ++k) {
    int idx = t + k * 256;
    int c = idx / 12, sq0 = (idx % 12) * 4;
    float4 xv = ((const float4*)xn)[idx];
    float4 gv = ((const float4*)gp)[idx];
    float4 bv = ((const float4*)bp)[idx];
    float4 o;
    o.x = (xv.x * sS[sq0]     - mu) * rstd * gv.x + bv.x;
    o.y = (xv.y * sS[sq0 + 1] - mu) * rstd * gv.y + bv.y;
    o.z = (xv.z * sS[sq0 + 2] - mu) * rstd * gv.z + bv.z;
    o.w = (xv.w * sS[sq0 + 3] - mu) * rstd * gv.w + bv.w;
    ((float4*)yn)[idx] = o;
    float* d = ts + c * 49 + sq0;
    d[0] = o.x; d[1] = o.y; d[2] = o.z; d[3] = o.w;
  }
  __syncthreads();
  __hip_bfloat16* dst = yb + (size_t)n * LNSZ + bx * 128;
#pragma unroll
  for (int k = 0; k < 12; ++k) {
    int idx = t + k * 256;
    int s = idx >> 6, cp = idx & 63;
    __hip_bfloat162 p;
    p.x = __float2bfloat16(ts[(cp * 2) * 49 + s]);
    p.y = __float2bfloat16(ts[(cp * 2 + 1) * 49 + s]);
    *(__hip_bfloat162*)(dst + (size_t)s * 512 + cp * 2) = p;
  }
}

// conv2 with fused residual + LN2 stats (round-0 geometry):
// v = y + Wc2@ub; stats2[n][oc]={S,S2}. Grid (4 o-chunks of 128, 64 n).
__global__ __launch_bounds__(256) void conv2_fused(
    const __hip_bfloat16* __restrict__ Wb, const __hip_bfloat16* __restrict__ inb,
    const float* __restrict__ y, float* __restrict__ v,
    float2* __restrict__ stats2) {
  const int oc = blockIdx.x, n = blockIdx.y;
  const int w = threadIdx.x >> 6, lane = threadIdx.x & 63;
  const int c16 = lane & 15, quad = lane >> 4;
  const int obase = oc * 128 + w * 32;

  const __hip_bfloat16* A0 = Wb + (size_t)(obase + c16) * 512 + quad * 8;
  const __hip_bfloat16* A1 = A0 + 16 * 512;
  const __hip_bfloat16* B0 = inb + (size_t)n * LNSZ + (size_t)c16 * 512 + quad * 8;

  floatx4 zero = {0.f, 0.f, 0.f, 0.f};
  floatx4 acc[2][3];
#pragma unroll
  for (int i = 0; i < 2; ++i)
#pragma unroll
    for (int j = 0; j < 3; ++j) acc[i][j] = zero;

  bf16x8 a[2], b[3];
  a[0] = *(const bf16x8*)(A0);
  a[1] = *(const bf16x8*)(A1);
  b[0] = *(const bf16x8*)(B0);
  b[1] = *(const bf16x8*)(B0 + 16 * 512);
  b[2] = *(const bf16x8*)(B0 + 32 * 512);

  for (int k = 0; k < 480; k += 32) {
    bf16x8 an[2], bn[3];
    const int k2 = k + 32;
    an[0] = *(const bf16x8*)(A0 + k2);
    an[1] = *(const bf16x8*)(A1 + k2);
    bn[0] = *(const bf16x8*)(B0 + k2);
    bn[1] = *(const bf16x8*)(B0 + 16 * 512 + k2);
    bn[2] = *(const bf16x8*)(B0 + 32 * 512 + k2);
#pragma unroll
    for (int i = 0; i < 2; ++i)
#pragma unroll
      for (int j = 0; j < 3; ++j)
        acc[i][j] = __builtin_amdgcn_mfma_f32_16x16x32_bf16(a[i], b[j],
                                                            acc[i][j], 0, 0, 0);
    a[0] = an[0]; a[1] = an[1];
    b[0] = bn[0]; b[1] = bn[1]; b[2] = bn[2];
  }
#pragma unroll
  for (int i = 0; i < 2; ++i)
#pragma unroll
    for (int j = 0; j < 3; ++j)
      acc[i][j] = __builtin_amdgcn_mfma_f32_16x16x32_bf16(a[i], b[j],
                                                          acc[i][j], 0, 0, 0);

  const float* yn = y + (size_t)n * LNSZ;
  float* vn = v + (size_t)n * LNSZ;
  float sum = 0.f, sq = 0.f;
#pragma unroll
  for (int i = 0; i < 2; ++i)
#pragma unroll
    for (int r = 0; r < 4; ++r) {
      const int o = obase + i * 16 + quad * 4 + r;
#pragma unroll
      for (int j = 0; j < 3; ++j) {
        const int s = j * 16 + c16;
        float val = acc[i][j][r] + yn[(size_t)o * HW + s];
        vn[(size_t)o * HW + s] = val;
        sum += val;
        sq += val * val;
      }
    }
  block_reduce2(sum, sq);
  if (threadIdx.x == 0) stats2[n * 4 + oc] = make_float2(sum, sq);
}

__global__ __launch_bounds__(256) void ln2_norm(
    const float* __restrict__ v, const float2* __restrict__ stats2,
    const float* __restrict__ g2, const float* __restrict__ b2,
    float* __restrict__ out) {
  const int bx = blockIdx.x, n = blockIdx.y, t = threadIdx.x;
  __shared__ float smu, srstd;
  if (t == 0) {
    float s1 = 0.f, s2 = 0.f;
#pragma unroll
    for (int k = 0; k < 4; ++k) {
      float2 p = stats2[n * 4 + k];
      s1 += p.x; s2 += p.y;
    }
    float mu = s1 * (1.0f / LNSZ);
    float var = s2 * (1.0f / LNSZ) - mu * mu;
    smu = mu;
    srstd = 1.0f / sqrtf(var + 1e-5f);
  }
  __syncthreads();
  const float mu = smu, rstd = srstd;
  const size_t chunk = (size_t)bx * 6144;
  const float* vn = v + (size_t)n * LNSZ + chunk;
  float* on = out + (size_t)n * LNSZ + chunk;
  const float* gp = g2 + chunk;
  const float* bp = b2 + chunk;
#pragma unroll
  for (int k = 0; k < 6; ++k) {
    int idx = t + k * 256;
    float4 vv = ((const float4*)vn)[idx];
    float4 gv = ((const float4*)gp)[idx];
    float4 bv = ((const float4*)bp)[idx];
    float4 o;
    o.x = (vv.x - mu) * rstd * gv.x + bv.x;
    o.y = (vv.y - mu) * rstd * gv.y + bv.y;
    o.z = (vv.z - mu) * rstd * gv.z + bv.z;
    o.w = (vv.w - mu) * rstd * gv.w + bv.w;
    ((float4*)on)[idx] = o;
  }
}

extern "C" void kernel_launch(void* const* d_in, const int* in_sizes, int n_in,
                              void* d_out, int out_size, void* d_ws, size_t ws_size,
                              hipStream_t stream) {
  const float* x   = (const float*)d_in[0];
  const float* tw  = (const float*)d_in[1];
  const float* tb  = (const float*)d_in[2];
  const float* pw  = (const float*)d_in[3];
  const float* pb  = (const float*)d_in[4];
  const float* c1w = (const float*)d_in[5];
  const float* c2w = (const float*)d_in[6];
  const float* g1  = (const float*)d_in[7];
  const float* b1  = (const float*)d_in[8];
  const float* g2  = (const float*)d_in[9];
  const float* b2  = (const float*)d_in[10];

  float* ws = (float*)d_ws;
  __hip_bfloat16* Wb = (__hip_bfloat16*)(ws + WB_OFF);
  float* bcat        = ws + BC_OFF;
  float* S           = ws + S_OFF;
  float* cxp         = ws + CXP_OFF;
  float* cx2p        = ws + CX2_OFF;
  float2* st2        = (float2*)(ws + ST2_OFF);
  __hip_bfloat16* xb = (__hip_bfloat16*)(ws + XB_OFF);
  __hip_bfloat16* tp = (__hip_bfloat16*)(ws + TP_OFF);
  __hip_bfloat16* yb = (__hip_bfloat16*)(ws + YB_OFF);
  __hip_bfloat16* ub = (__hip_bfloat16*)(ws + UB_OFF);
  __hip_bfloat16* Pp = (__hip_bfloat16*)(ws + PP_OFF);
  float* y           = ws + YY_OFF;
  float* v           = ws + VV_OFF;
  float* out         = (float*)d_out;

  // weights pack + bias cat + S zero (blocks 0..767) and x transpose + LN1
  // column stats (blocks 768..1023), one launch
  prep_all<<<1024, 256, 0, stream>>>(tw, pw, c1w, c2w, tb, pb, x,
                                     Wb, bcat, S, xb, cxp, cx2p);
  // theta+phi projection (round-0 geometry) + fused 2x2 pool -> tp and Pp
  gemm_bf16out<<<dim3(4, NN), 256, 0, stream>>>(Wb, xb, bcat, tp, 0, Pp);
  // score GEMM + pool-max + query-sum -> S (atomic)
  dgemm_fused<<<dim3(16, 24), 256, 0, stream>>>(tp, Pp, S);
  // LN1 stats (fused) + apply -> y fp32 + yb bf16 (fused transpose)
  ln1_norm_tr<<<dim3(4, NN), 256, 0, stream>>>(x, S, cxp, cx2p, g1, b1, y, yb);
  // conv1 + relu -> ub bf16 [s][c]
  gemm_bf16out<<<dim3(4, NN), 256, 0, stream>>>(Wb + 512 * 512, yb, nullptr, ub, 1,
                                                nullptr);
  // conv2 + residual + LN2 stats
  conv2_fused<<<dim3(4, NN), 256, 0, stream>>>(Wb + 1024 * 512, ub, y, v, st2);
  ln2_norm<<<dim3(4, NN), 256, 0, stream>>>(v, st2, g2, b2, out);
}